// Round 1
// baseline (865.501 us; speedup 1.0000x reference)
//
#include <hip/hip_runtime.h>

#define Nn 50000
#define Rr 16
#define Dd 64
#define Fin 128
#define Ee 100000

typedef __attribute__((ext_vector_type(8))) short short8;
typedef __attribute__((ext_vector_type(4))) float f32x4;

__device__ inline unsigned short f2bf(float x) {
  union { float f; unsigned u; } v; v.f = x;
  unsigned u = v.u;
  unsigned r = (u + 0x7FFFu + ((u >> 16) & 1u)) >> 16;  // RNE
  return (unsigned short)r;
}

__device__ inline void atomic_add_f32(float* p, float v) {
  __hip_atomic_fetch_add(p, v, __ATOMIC_RELAXED, __HIP_MEMORY_SCOPE_AGENT);
}

// emb0[n,d] = sum_k x[n,k] * ent_emb[k,d]
__global__ __launch_bounds__(256) void init_gemm(const float* __restrict__ x,
                                                 const float* __restrict__ w,
                                                 float* __restrict__ out) {
  int wave = threadIdx.x >> 6, lane = threadIdx.x & 63;
  int row = blockIdx.x * 4 + wave;
  if (row >= Nn) return;
  const float* xr = x + (long)row * Fin;
  float acc = 0.f;
#pragma unroll 8
  for (int k = 0; k < Fin; ++k)
    acc = fmaf(xr[k], w[k * Dd + lane], acc);  // xr[k] uniform -> L1 broadcast
  out[row * Dd + lane] = acc;
}

// Per-edge fused transform+scatter:
//   out[row] += val * (relu?(emb[col]) @ W_r^T)
// Wave batches 16 edges of one relation; 8x mfma 16x16x32 bf16 per batch.
#define GROUPS_PER_WAVE 8
__global__ __launch_bounds__(256) void layer_scatter(
    const float* __restrict__ emb, const float* __restrict__ Wl,
    const int* __restrict__ erow, const int* __restrict__ ecol,
    const float* __restrict__ eval, float* __restrict__ out, int relu_in) {
  const int r = blockIdx.y;
  const int wave = threadIdx.x >> 6, lane = threadIdx.x & 63;
  const int nt = lane & 15, quad = lane >> 4;
  const float* Wr = Wl + r * Dd * Dd;

  // B = W_r^T so B[k=e][n=d] = W_r[d][e]; lane reads contiguous row d.
  short8 bfrag[4][2];
#pragma unroll
  for (int dt = 0; dt < 4; ++dt) {
#pragma unroll
    for (int ks = 0; ks < 2; ++ks) {
      const float* wp = Wr + (dt * 16 + nt) * Dd + ks * 32 + quad * 8;
      short8 b;
#pragma unroll
      for (int j = 0; j < 8; ++j) b[j] = (short)f2bf(wp[j]);
      bfrag[dt][ks] = b;
    }
  }

  const float rz = relu_in ? 0.f : -__builtin_inff();  // fmaxf(x,-inf)=x
  const long be = (long)r * Ee;
  const int eg0 = (blockIdx.x * 4 + wave) * (16 * GROUPS_PER_WAVE);

  for (int it = 0; it < GROUPS_PER_WAVE; ++it) {
    int eg = eg0 + it * 16;
    if (eg >= Ee) break;  // uniform per wave
    int me = eg + nt;
    bool mv = me < Ee;
    int col = mv ? ecol[be + me] : 0;
    float val = mv ? eval[be + me] : 0.f;
    const float* ep = emb + col * Dd;

    short8 afrag[2];
#pragma unroll
    for (int ks = 0; ks < 2; ++ks) {
      short8 a;
#pragma unroll
      for (int j = 0; j < 8; ++j) {
        float xv = fmaxf(ep[ks * 32 + quad * 8 + j], rz);
        a[j] = (short)f2bf(val * xv);
      }
      afrag[ks] = a;
    }

    f32x4 acc[4];
#pragma unroll
    for (int dt = 0; dt < 4; ++dt) {
      f32x4 c = {0.f, 0.f, 0.f, 0.f};
      c = __builtin_amdgcn_mfma_f32_16x16x32_bf16(afrag[0], bfrag[dt][0], c, 0, 0, 0);
      c = __builtin_amdgcn_mfma_f32_16x16x32_bf16(afrag[1], bfrag[dt][1], c, 0, 0, 0);
      acc[dt] = c;
    }

    // D[m=quad*4+reg][d=dt*16+nt] -> atomic scatter to out[row]
#pragma unroll
    for (int reg = 0; reg < 4; ++reg) {
      int em = eg + quad * 4 + reg;
      if (em < Ee) {
        int rw = erow[be + em];
        float* op = out + rw * Dd + nt;
#pragma unroll
        for (int dt = 0; dt < 4; ++dt)
          atomic_add_f32(op + dt * 16, acc[dt][reg]);
      }
    }
  }
}

__global__ __launch_bounds__(256) void normalize_k(const float* __restrict__ in,
                                                   float* __restrict__ out) {
  int wave = threadIdx.x >> 6, lane = threadIdx.x & 63;
  int row = blockIdx.x * 4 + wave;
  if (row >= Nn) return;
  float v = fmaxf(in[row * Dd + lane], 0.f);  // final relu
  float s = v * v;
#pragma unroll
  for (int off = 32; off >= 1; off >>= 1)
    s += __shfl_xor(s, off, 64);
  float dn = fmaxf(sqrtf(s), 1e-12f);
  out[row * Dd + lane] = v / dn;
}

extern "C" void kernel_launch(void* const* d_in, const int* in_sizes, int n_in,
                              void* d_out, int out_size, void* d_ws, size_t ws_size,
                              hipStream_t stream) {
  const float* x   = (const float*)d_in[0];
  const float* ent = (const float*)d_in[1];
  const float* rel = (const float*)d_in[2];
  const int* erow  = (const int*)d_in[3];
  const int* ecol  = (const int*)d_in[4];
  const float* ev  = (const float*)d_in[5];
  float* out = (float*)d_out;

  float* emb_a = (float*)d_ws;
  float* emb_b = emb_a + (size_t)Nn * Dd;
  const size_t SZ = (size_t)Nn * Dd * sizeof(float);

  init_gemm<<<dim3((Nn + 3) / 4), 256, 0, stream>>>(x, ent, emb_a);
  hipMemsetAsync(emb_b, 0, SZ, stream);

  dim3 sg((Ee + 511) / 512, Rr);
  layer_scatter<<<sg, 256, 0, stream>>>(emb_a, rel, erow, ecol, ev, emb_b, 0);

  hipMemsetAsync(emb_a, 0, SZ, stream);
  layer_scatter<<<sg, 256, 0, stream>>>(emb_b, rel + Rr * Dd * Dd, erow, ecol, ev, emb_a, 1);

  normalize_k<<<dim3((Nn + 3) / 4), 256, 0, stream>>>(emb_a, out);
}

// Round 2
// 735.456 us; speedup vs baseline: 1.1768x; 1.1768x over previous
//
#include <hip/hip_runtime.h>

#define Nn 50000
#define Rr 16
#define Dd 64
#define Fin 128
#define Ee 100000

typedef __attribute__((ext_vector_type(8))) short short8;
typedef __attribute__((ext_vector_type(4))) float f32x4;
typedef unsigned short ushort_t;
typedef unsigned int uint;

__device__ inline ushort_t f2bf(float x) {
  union { float f; unsigned u; } v; v.f = x;
  unsigned u = v.u;
  return (ushort_t)((u + 0x7FFFu + ((u >> 16) & 1u)) >> 16);  // RNE
}
__device__ inline float bf2f(ushort_t h) {
  union { unsigned u; float f; } v; v.u = ((unsigned)h) << 16; return v.f;
}

// ---------------- init: emb0 = x @ ent_emb, bf16 out ----------------
__global__ __launch_bounds__(256) void init_gemm(const float* __restrict__ x,
                                                 const float* __restrict__ w,
                                                 ushort_t* __restrict__ out) {
  int wave = threadIdx.x >> 6, lane = threadIdx.x & 63;
  int row = blockIdx.x * 4 + wave;
  if (row >= Nn) return;
  const float* xr = x + (long)row * Fin;
  float acc = 0.f;
#pragma unroll 8
  for (int k = 0; k < Fin; ++k)
    acc = fmaf(xr[k], w[k * Dd + lane], acc);  // xr[k] wave-uniform -> broadcast
  out[row * Dd + lane] = f2bf(acc);
}

// ---------------- CSR build ----------------
__global__ __launch_bounds__(256) void hist_k(const int* __restrict__ erow,
                                              int* __restrict__ cnt) {
  int e = blockIdx.x * 256 + threadIdx.x;
  int r = blockIdx.y;
  if (e < Ee) atomicAdd(&cnt[erow[r * Ee + e]], 1);
}

// single block, 1024 threads: exclusive scan of cnt[0..Nn) -> offs, cursor(=cnt)
__global__ __launch_bounds__(1024) void scan_k(int* __restrict__ cnt,
                                               int* __restrict__ offs) {
  __shared__ int part[1024];
  int t = threadIdx.x;
  const int CH = (Nn + 1023) / 1024;  // 49
  int base = t * CH;
  int s = 0;
  for (int i = 0; i < CH; ++i) {
    int idx = base + i;
    if (idx < Nn) s += cnt[idx];
  }
  part[t] = s;
  __syncthreads();
  for (int off = 1; off < 1024; off <<= 1) {
    int v = (t >= off) ? part[t - off] : 0;
    __syncthreads();
    part[t] += v;
    __syncthreads();
  }
  int run = part[t] - s;  // exclusive prefix
  for (int i = 0; i < CH; ++i) {
    int idx = base + i;
    if (idx < Nn) {
      int c = cnt[idx];
      offs[idx] = run;
      cnt[idx] = run;  // cursor start
      run += c;
    }
  }
  if (t == 1023) offs[Nn] = run;  // total = Rr*Ee
}

__global__ __launch_bounds__(256) void scatter_k(const int* __restrict__ erow,
                                                 const int* __restrict__ ecol,
                                                 const float* __restrict__ ev,
                                                 int* __restrict__ cursor,
                                                 uint2* __restrict__ ed) {
  int e = blockIdx.x * 256 + threadIdx.x;
  int r = blockIdx.y;
  if (e >= Ee) return;
  long idx = (long)r * Ee + e;
  int row = erow[idx];
  int pos = atomicAdd(&cursor[row], 1);
  ed[pos] = make_uint2(((unsigned)r << 16) | (unsigned)ecol[idx],
                       __float_as_uint(ev[idx]));
}

// ---------------- W -> bf16 ----------------
__global__ __launch_bounds__(256) void convw_k(const float* __restrict__ rel,
                                               ushort_t* __restrict__ wbf) {
  int i = blockIdx.x * 256 + threadIdx.x;
  if (i < 2 * Rr * Dd * Dd) wbf[i] = f2bf(rel[i]);
}

// ---------------- Y_r = emb @ W_r^T for all r, bf16 out ----------------
// Y[r][n][d] = sum_e emb[n][e] * W[r][d][e]
__global__ __launch_bounds__(256) void ygemm_k(const ushort_t* __restrict__ emb,
                                               const ushort_t* __restrict__ wbf,
                                               ushort_t* __restrict__ Y) {
  int wave = threadIdx.x >> 6, lane = threadIdx.x & 63;
  int nt = lane & 15, quad = lane >> 4;
  int tile = blockIdx.x * 4 + wave;  // 16-row tile; Nn/16 = 3125 exact
  if (tile >= Nn / 16) return;

  const ushort_t* ar = emb + (unsigned)(tile * 16 + nt) * Dd + quad * 8;
  short8 a0 = *(const short8*)(ar);
  short8 a1 = *(const short8*)(ar + 32);

  for (int r = 0; r < Rr; ++r) {
    const ushort_t* wr = wbf + r * Dd * Dd;
    f32x4 acc[4];
#pragma unroll
    for (int dt = 0; dt < 4; ++dt) {
      const ushort_t* bp = wr + (unsigned)(dt * 16 + nt) * Dd + quad * 8;
      short8 b0 = *(const short8*)(bp);
      short8 b1 = *(const short8*)(bp + 32);
      f32x4 c = {0.f, 0.f, 0.f, 0.f};
      c = __builtin_amdgcn_mfma_f32_16x16x32_bf16(a0, b0, c, 0, 0, 0);
      c = __builtin_amdgcn_mfma_f32_16x16x32_bf16(a1, b1, c, 0, 0, 0);
      acc[dt] = c;
    }
    ushort_t* yr = Y + ((unsigned)r * Nn + (unsigned)tile * 16) * Dd;
#pragma unroll
    for (int dt = 0; dt < 4; ++dt)
#pragma unroll
      for (int reg = 0; reg < 4; ++reg)
        yr[(unsigned)(quad * 4 + reg) * Dd + dt * 16 + nt] = f2bf(acc[dt][reg]);
  }
}

// ---------------- gather: out[row] = sum_{edges->row} val * Y[rel][col] ----------------
__global__ __launch_bounds__(256) void gather_k(const ushort_t* __restrict__ Y,
                                                const int* __restrict__ offs,
                                                const uint2* __restrict__ ed,
                                                ushort_t* __restrict__ embout,
                                                float* __restrict__ finout,
                                                int fin) {
  int wave = threadIdx.x >> 6, lane = threadIdx.x & 63;
  int row = blockIdx.x * 4 + wave;
  if (row >= Nn) return;
  int s = offs[row], e = offs[row + 1];
  float acc = 0.f;
  int i = s, e4 = s + ((e - s) & ~3);
  for (; i < e4; i += 4) {
    uint2 q0 = ed[i], q1 = ed[i + 1], q2 = ed[i + 2], q3 = ed[i + 3];
    float y0 = bf2f(Y[((q0.x >> 16) * (unsigned)Nn + (q0.x & 0xFFFFu)) * Dd + lane]);
    float y1 = bf2f(Y[((q1.x >> 16) * (unsigned)Nn + (q1.x & 0xFFFFu)) * Dd + lane]);
    float y2 = bf2f(Y[((q2.x >> 16) * (unsigned)Nn + (q2.x & 0xFFFFu)) * Dd + lane]);
    float y3 = bf2f(Y[((q3.x >> 16) * (unsigned)Nn + (q3.x & 0xFFFFu)) * Dd + lane]);
    acc = fmaf(__uint_as_float(q0.y), y0, acc);
    acc = fmaf(__uint_as_float(q1.y), y1, acc);
    acc = fmaf(__uint_as_float(q2.y), y2, acc);
    acc = fmaf(__uint_as_float(q3.y), y3, acc);
  }
  for (; i < e; ++i) {
    uint2 q = ed[i];
    acc = fmaf(__uint_as_float(q.y),
               bf2f(Y[((q.x >> 16) * (unsigned)Nn + (q.x & 0xFFFFu)) * Dd + lane]),
               acc);
  }
  float v = fmaxf(acc, 0.f);
  if (fin) {
    float ss = v * v;
#pragma unroll
    for (int off = 32; off >= 1; off >>= 1) ss += __shfl_xor(ss, off, 64);
    finout[(unsigned)row * Dd + lane] = v / fmaxf(sqrtf(ss), 1e-12f);
  } else {
    embout[(unsigned)row * Dd + lane] = f2bf(v);
  }
}

extern "C" void kernel_launch(void* const* d_in, const int* in_sizes, int n_in,
                              void* d_out, int out_size, void* d_ws, size_t ws_size,
                              hipStream_t stream) {
  const float* x   = (const float*)d_in[0];
  const float* ent = (const float*)d_in[1];
  const float* rel = (const float*)d_in[2];
  const int* erow  = (const int*)d_in[3];
  const int* ecol  = (const int*)d_in[4];
  const float* ev  = (const float*)d_in[5];
  float* out = (float*)d_out;

  // workspace carve-up (all 256B-aligned by construction)
  char* p = (char*)d_ws;
  ushort_t* emb_a = (ushort_t*)p;               p += (size_t)Nn * Dd * 2;       // 6.4 MB
  ushort_t* emb_b = (ushort_t*)p;               p += (size_t)Nn * Dd * 2;       // 6.4 MB
  ushort_t* wbf   = (ushort_t*)p;               p += (size_t)2 * Rr * Dd * Dd * 2; // 256 KB
  ushort_t* Y     = (ushort_t*)p;               p += (size_t)Rr * Nn * Dd * 2;  // 102.4 MB
  int* offs       = (int*)p;                    p += (size_t)(Nn + 1) * 4;
  int* cnt        = (int*)p;                    p += (size_t)Nn * 4;            // counts then cursor
  uint2* ed       = (uint2*)p;                  p += (size_t)Rr * Ee * 8;       // 12.8 MB

  // CSR build (shared by both layers)
  hipMemsetAsync(cnt, 0, (size_t)Nn * 4, stream);
  hist_k<<<dim3((Ee + 255) / 256, Rr), 256, 0, stream>>>(erow, cnt);
  scan_k<<<1, 1024, 0, stream>>>(cnt, offs);
  scatter_k<<<dim3((Ee + 255) / 256, Rr), 256, 0, stream>>>(erow, ecol, ev, cnt, ed);

  convw_k<<<(2 * Rr * Dd * Dd + 255) / 256, 256, 0, stream>>>(rel, wbf);
  init_gemm<<<(Nn + 3) / 4, 256, 0, stream>>>(x, ent, emb_a);

  // layer 1
  ygemm_k<<<(Nn / 16 + 3) / 4, 256, 0, stream>>>(emb_a, wbf, Y);
  gather_k<<<(Nn + 3) / 4, 256, 0, stream>>>(Y, offs, ed, emb_b, nullptr, 0);
  // layer 2 (+ fused relu + L2 normalize)
  ygemm_k<<<(Nn / 16 + 3) / 4, 256, 0, stream>>>(emb_b, wbf + Rr * Dd * Dd, Y);
  gather_k<<<(Nn + 3) / 4, 256, 0, stream>>>(Y, offs, ed, nullptr, out, 1);
}